// Round 14
// baseline (11.862 us; speedup 1.0000x reference)
//
#include <hip/hip_runtime.h>
#include <hip/hip_bf16.h>

#define MM 2048
#define NN 32
#define BINS 512
#define KG 16                   // slot-groups per row; block g owns slots q ≡ g (mod 16)
#define NB (NN * KG)            // 512 blocks = 2 per CU (independent barrier domains pipeline)
#define TPB 512
#define SLOTS 128               // 4-lane teams per block (~64 active: ceil(P/16) ~ 64-80)
#define SRT_SZ 2080
#define W 64                    // window elements (8 float4/lane, 2 lanes/window)
#define SCALE 144.26950408889634f      // 100 * log2(e)
#define INV_SB (51.2f / SCALE)         // scaled value -> bin coordinate

#if __has_builtin(__builtin_amdgcn_exp2f)
#define EXP2F(x) __builtin_amdgcn_exp2f(x)
#else
#define EXP2F(x) exp2f(x)
#endif

// ---------------- fused: in-LDS packed counting sort + windowed rank sums ----------------
// b = g*32 + n (n-minor). Block sorts row n in LDS (redundant across 16 groups), then
// evaluates positive slots q = g + 16*si. Packed hist: pos in high 16 bits, neg in low.
__global__ __launch_bounds__(TPB) void smoothap_fused(
    const float* __restrict__ sim, const float* __restrict__ tgt,
    float* __restrict__ partial)
{
    __shared__ float srt[SRT_SZ];   // [0,Ppad) sorted scaled positives; [Ppad,+Mnpad) negatives
    __shared__ float tqs[1280];     // t of sorted positives (P <= 1280: +11 sigma)
    __shared__ int   h[BINS];       // packed: hist -> exclusive offsets -> end offsets
    __shared__ int   wi[8];
    __shared__ float wden[8];
    __shared__ int   shTot;
    __shared__ float red[SLOTS];
    __shared__ float w2[2];

    const int b    = blockIdx.x;
    const int n    = b & 31;
    const int g    = b >> 5;        // 0..15
    const int tid  = threadIdx.x;
    const int lane = tid & 63;
    const int wv   = tid >> 6;

    if (tid < BINS) h[tid] = 0;
    __syncthreads();

    // ---- load 4 elems/thread, packed histogram, denom ----
    float4 s4 = reinterpret_cast<const float4*>(sim + n * MM)[tid];
    float4 t4 = reinterpret_cast<const float4*>(tgt + n * MM)[tid];
    float sv[4] = {s4.x, s4.y, s4.z, s4.w};
    float tv[4] = {t4.x, t4.y, t4.z, t4.w};

    int bi[4], mk[4];
    float dt = 0.0f;
#pragma unroll
    for (int e = 0; e < 4; ++e) {
        int bb = (int)(sv[e] * 51.2f + 256.0f);
        bb = (bb < 0) ? 0 : ((bb > BINS - 1) ? BINS - 1 : bb);
        bi[e] = bb;
        mk[e] = (tv[e] > 0.5f) ? 1 : 0;
        atomicAdd(&h[bb], mk[e] ? 0x10000 : 1);
        if (mk[e]) dt += tv[e];
    }
    dt += __shfl_xor(dt, 1);
    dt += __shfl_xor(dt, 2);
    dt += __shfl_xor(dt, 4);
    dt += __shfl_xor(dt, 8);
    dt += __shfl_xor(dt, 16);
    dt += __shfl_xor(dt, 32);
    if (lane == 0) wden[wv] = dt;
    __syncthreads();                     // hist + wden complete

    // ---- exclusive scan of packed hist (1 bin/thread; high/low scanned together) ----
    const int v = h[tid];
    int incl = v;
#pragma unroll
    for (int d = 1; d < 64; d <<= 1) {
        int u = __shfl_up(incl, d);
        if (lane >= d) incl += u;
    }
    if (lane == 63) wi[wv] = incl;
    __syncthreads();                     // wave totals ready; all h reads done
    int offs = incl - v;
#pragma unroll
    for (int k = 0; k < 8; ++k) if (k < wv) offs += wi[k];
    h[tid] = offs;
    if (tid == TPB - 1) shTot = offs + v;
    __syncthreads();                     // scanned offsets + totals ready

    const int P     = shTot >> 16;
    const int Ppad  = (P + 3) & ~3;
    const int Mn    = MM - P;
    const int Mnpad = (Mn + 3) & ~3;
    float denom = 0.0f;
#pragma unroll
    for (int k = 0; k < 8; ++k) denom += wden[k];

    // ---- scatter (packed atomics; pos bumps high16, neg bumps low16) ----
#pragma unroll
    for (int e = 0; e < 4; ++e) {
        if (mk[e]) {
            int old = atomicAdd(&h[bi[e]], 0x10000);
            int q = old >> 16;
            srt[q] = sv[e] * SCALE;
            tqs[q] = tv[e];
        } else {
            int old = atomicAdd(&h[bi[e]], 1);
            srt[Ppad + (old & 0xFFFF)] = sv[e] * SCALE;
        }
    }
    if (tid < 4) {   // pads: exp2(+1e30)=inf -> rcp(inf)=0, contribute nothing
        if (P + tid < Ppad)   srt[P + tid] = -1e30f;
        if (Mn + tid < Mnpad) srt[Ppad + Mn + tid] = -1e30f;
    }
    __syncthreads();                     // sorted arrays + h bin-end offsets ready

    // ---- windowed rank sums: 4 lanes/slot, 2 lanes per 64-elem window ----
    const int ty = tid >> 2;   // team 0..127
    const int tx = tid & 3;
    const float4* sa4 = reinterpret_cast<const float4*>(srt);

    float vacc = 0.0f;
    for (int si = ty; ; si += SLOTS) {
        const int q = g + KG * si;       // interleaved: block g owns q ≡ g (mod 16)
        if (q >= P) break;
        const float zi = srt[q];

        int bp = (q - W / 2) & ~3;
        bp = (bp < 0) ? 0 : bp;
        bp = (bp > Ppad - W) ? (Ppad - W) : bp;

        // neg insertion rank ~ bin end-offset (overshoot <= bin occupancy; r~0 side)
        int bb = (int)(zi * INV_SB + 256.0f);
        bb = (bb < 0) ? 0 : ((bb > BINS - 1) ? BINS - 1 : bb);
        const int lo = h[bb] & 0xFFFF;
        int bn = (lo - W / 2) & ~3;
        bn = (bn < 0) ? 0 : bn;
        bn = (bn > Mnpad - W) ? (Mnpad - W) : bn;

        const int c0 = (tx < 2) ? (bp >> 2) + tx
                                : (Ppad >> 2) + (bn >> 2) + (tx - 2);

        float acc = 0.0f;
#define EVAL(s)                                                    \
        {                                                          \
            float z = zi - (s);                                    \
            acc += __builtin_amdgcn_rcpf(1.0f + EXP2F(z));         \
        }
#pragma unroll
        for (int k = 0; k < 8; ++k) {        // 8 chunks stride 2 = 32 evals/lane
            float4 vv = sa4[c0 + 2 * k];
            EVAL(vv.x); EVAL(vv.y); EVAL(vv.z); EVAL(vv.w);
        }
#undef EVAL

        acc += __shfl_xor(acc, 1);               // sum within each window pair
        const float other = __shfl_xor(acc, 2);  // tx==0 receives neg-window sum
        if (tx == 0) {
            float wp = acc;      // pos window (self contributes exactly 0.5)
            float wn = other;
            int cAp = P - (bp + W);  if (cAp < 0) cAp = 0;
            int cAn = Mn - (bn + W); if (cAn < 0) cAn = 0;
            float pos_rk = (float)cAp + wp + 0.5f;   // -0.5 diag + 1.0
            float all_rk = pos_rk + (float)cAn + wn;
            vacc += pos_rk * tqs[q] / all_rk;
        }
    }
    if (tx == 0) red[ty] = vacc;
    __syncthreads();

    if (tid < SLOTS) {
        float vv = red[tid];
        vv += __shfl_xor(vv, 1);
        vv += __shfl_xor(vv, 2);
        vv += __shfl_xor(vv, 4);
        vv += __shfl_xor(vv, 8);
        vv += __shfl_xor(vv, 16);
        vv += __shfl_xor(vv, 32);
        if (lane == 0) w2[tid >> 6] = vv;
    }
    __syncthreads();
    if (tid == 0) partial[b] = (w2[0] + w2[1]) / denom;
}

// ---------------- finisher: two waves sum 512 pre-divided partials ----------------
__global__ __launch_bounds__(128) void smoothap_final(
    const float* __restrict__ partial, float* __restrict__ out)
{
    __shared__ float w2[2];
    const int tid = threadIdx.x;
    float4 a = reinterpret_cast<const float4*>(partial)[tid];  // 128*4 = 512
    float v = (a.x + a.y) + (a.z + a.w);
    v += __shfl_xor(v, 1);
    v += __shfl_xor(v, 2);
    v += __shfl_xor(v, 4);
    v += __shfl_xor(v, 8);
    v += __shfl_xor(v, 16);
    v += __shfl_xor(v, 32);
    if ((tid & 63) == 0) w2[tid >> 6] = v;
    __syncthreads();
    if (tid == 0) out[0] = 1.0f - (w2[0] + w2[1]) * (1.0f / 32.0f);
}

extern "C" void kernel_launch(void* const* d_in, const int* in_sizes, int n_in,
                              void* d_out, int out_size, void* d_ws, size_t ws_size,
                              hipStream_t stream) {
    const float* sim = (const float*)d_in[0];
    const float* tgt = (const float*)d_in[1];
    float* out = (float*)d_out;
    float* partial = (float*)d_ws;   // 512 floats (16B-aligned)

    smoothap_fused<<<dim3(NB), dim3(TPB), 0, stream>>>(sim, tgt, partial);
    smoothap_final<<<dim3(1), dim3(128), 0, stream>>>(partial, out);
}

// Round 15
// 11.227 us; speedup vs baseline: 1.0565x; 1.0565x over previous
//
#include <hip/hip_runtime.h>
#include <hip/hip_bf16.h>

#define MM 2048
#define NN 32
#define BINS 512
#define KG 8                    // slot-groups per row; block g owns slots q ≡ g (mod 8)
#define NB (NN * KG)            // 256 blocks = 1 per CU
#define TPB 512
#define SLOTS 128               // 4-lane teams per block
#define SRT_SZ 2080
#define W 64                    // window elements (8 float4/lane, 2 lanes/window)
#define SCALE 144.26950408889634f      // 100 * log2(e)
#define INV_SB (51.2f / SCALE)         // scaled value -> bin coordinate

#if __has_builtin(__builtin_amdgcn_exp2f)
#define EXP2F(x) __builtin_amdgcn_exp2f(x)
#else
#define EXP2F(x) exp2f(x)
#endif

// ---------------- fused: in-LDS packed counting sort + windowed rank sums ----------------
// b = g*32 + n (n-minor). Block sorts row n in LDS (redundant across 8 groups), then
// evaluates positive slots q = g + 8*si. Packed hist: pos in high 16 bits, neg in low.
// Measured champion config (round 10: 11.25 us); loads issued before hist-zero.
__global__ __launch_bounds__(TPB) void smoothap_fused(
    const float* __restrict__ sim, const float* __restrict__ tgt,
    float* __restrict__ partial)
{
    __shared__ float srt[SRT_SZ];   // [0,Ppad) sorted scaled positives; [Ppad,+Mnpad) negatives
    __shared__ float tqs[1280];     // t of sorted positives (P <= 1280: +11 sigma)
    __shared__ int   h[BINS];       // packed: hist -> exclusive offsets -> end offsets
    __shared__ int   wi[8];
    __shared__ float wden[8];
    __shared__ int   shTot;
    __shared__ float red[SLOTS];
    __shared__ float w2[2];

    const int b    = blockIdx.x;
    const int n    = b & 31;
    const int g    = b >> 5;        // 0..7
    const int tid  = threadIdx.x;
    const int lane = tid & 63;
    const int wv   = tid >> 6;

    // issue global loads first so HBM/L3 latency hides under hist-zero + barrier
    float4 s4 = reinterpret_cast<const float4*>(sim + n * MM)[tid];
    float4 t4 = reinterpret_cast<const float4*>(tgt + n * MM)[tid];

    if (tid < BINS) h[tid] = 0;
    __syncthreads();

    // ---- packed histogram + denom ----
    float sv[4] = {s4.x, s4.y, s4.z, s4.w};
    float tv[4] = {t4.x, t4.y, t4.z, t4.w};

    int bi[4], mk[4];
    float dt = 0.0f;
#pragma unroll
    for (int e = 0; e < 4; ++e) {
        int bb = (int)(sv[e] * 51.2f + 256.0f);
        bb = (bb < 0) ? 0 : ((bb > BINS - 1) ? BINS - 1 : bb);
        bi[e] = bb;
        mk[e] = (tv[e] > 0.5f) ? 1 : 0;
        atomicAdd(&h[bb], mk[e] ? 0x10000 : 1);
        if (mk[e]) dt += tv[e];
    }
    dt += __shfl_xor(dt, 1);
    dt += __shfl_xor(dt, 2);
    dt += __shfl_xor(dt, 4);
    dt += __shfl_xor(dt, 8);
    dt += __shfl_xor(dt, 16);
    dt += __shfl_xor(dt, 32);
    if (lane == 0) wden[wv] = dt;
    __syncthreads();                     // hist + wden complete

    // ---- exclusive scan of packed hist (1 bin/thread; high/low scanned together) ----
    const int v = h[tid];
    int incl = v;
#pragma unroll
    for (int d = 1; d < 64; d <<= 1) {
        int u = __shfl_up(incl, d);
        if (lane >= d) incl += u;
    }
    if (lane == 63) wi[wv] = incl;
    __syncthreads();                     // wave totals ready; all h reads done
    int offs = incl - v;
#pragma unroll
    for (int k = 0; k < 8; ++k) if (k < wv) offs += wi[k];
    h[tid] = offs;
    if (tid == TPB - 1) shTot = offs + v;
    __syncthreads();                     // scanned offsets + totals ready

    const int P     = shTot >> 16;
    const int Ppad  = (P + 3) & ~3;
    const int Mn    = MM - P;
    const int Mnpad = (Mn + 3) & ~3;
    float denom = 0.0f;
#pragma unroll
    for (int k = 0; k < 8; ++k) denom += wden[k];

    // ---- scatter (packed atomics; pos bumps high16, neg bumps low16) ----
#pragma unroll
    for (int e = 0; e < 4; ++e) {
        if (mk[e]) {
            int old = atomicAdd(&h[bi[e]], 0x10000);
            int q = old >> 16;
            srt[q] = sv[e] * SCALE;
            tqs[q] = tv[e];
        } else {
            int old = atomicAdd(&h[bi[e]], 1);
            srt[Ppad + (old & 0xFFFF)] = sv[e] * SCALE;
        }
    }
    if (tid < 4) {   // pads: exp2(+1e30)=inf -> rcp(inf)=0, contribute nothing
        if (P + tid < Ppad)   srt[P + tid] = -1e30f;
        if (Mn + tid < Mnpad) srt[Ppad + Mn + tid] = -1e30f;
    }
    __syncthreads();                     // sorted arrays + h bin-end offsets ready

    // ---- windowed rank sums: 4 lanes/slot, 2 lanes per 64-elem window ----
    const int ty = tid >> 2;   // team 0..127
    const int tx = tid & 3;
    const float4* sa4 = reinterpret_cast<const float4*>(srt);

    float vacc = 0.0f;
    for (int si = ty; ; si += SLOTS) {
        const int q = g + KG * si;       // interleaved: block g owns q ≡ g (mod 8)
        if (q >= P) break;
        const float zi = srt[q];

        int bp = (q - W / 2) & ~3;
        bp = (bp < 0) ? 0 : bp;
        bp = (bp > Ppad - W) ? (Ppad - W) : bp;

        // neg insertion rank ~ bin end-offset (overshoot <= bin occupancy; r~0 side)
        int bb = (int)(zi * INV_SB + 256.0f);
        bb = (bb < 0) ? 0 : ((bb > BINS - 1) ? BINS - 1 : bb);
        const int lo = h[bb] & 0xFFFF;
        int bn = (lo - W / 2) & ~3;
        bn = (bn < 0) ? 0 : bn;
        bn = (bn > Mnpad - W) ? (Mnpad - W) : bn;

        const int c0 = (tx < 2) ? (bp >> 2) + tx
                                : (Ppad >> 2) + (bn >> 2) + (tx - 2);

        float acc = 0.0f;
#define EVAL(s)                                                    \
        {                                                          \
            float z = zi - (s);                                    \
            acc += __builtin_amdgcn_rcpf(1.0f + EXP2F(z));         \
        }
#pragma unroll
        for (int k = 0; k < 8; ++k) {        // 8 chunks stride 2 = 32 evals/lane
            float4 vv = sa4[c0 + 2 * k];
            EVAL(vv.x); EVAL(vv.y); EVAL(vv.z); EVAL(vv.w);
        }
#undef EVAL

        acc += __shfl_xor(acc, 1);               // sum within each window pair
        const float other = __shfl_xor(acc, 2);  // tx==0 receives neg-window sum
        if (tx == 0) {
            float wp = acc;      // pos window (self contributes exactly 0.5)
            float wn = other;
            int cAp = P - (bp + W);  if (cAp < 0) cAp = 0;
            int cAn = Mn - (bn + W); if (cAn < 0) cAn = 0;
            float pos_rk = (float)cAp + wp + 0.5f;   // -0.5 diag + 1.0
            float all_rk = pos_rk + (float)cAn + wn;
            vacc += pos_rk * tqs[q] / all_rk;
        }
    }
    if (tx == 0) red[ty] = vacc;
    __syncthreads();

    if (tid < SLOTS) {
        float vv = red[tid];
        vv += __shfl_xor(vv, 1);
        vv += __shfl_xor(vv, 2);
        vv += __shfl_xor(vv, 4);
        vv += __shfl_xor(vv, 8);
        vv += __shfl_xor(vv, 16);
        vv += __shfl_xor(vv, 32);
        if (lane == 0) w2[tid >> 6] = vv;
    }
    __syncthreads();
    if (tid == 0) partial[b] = (w2[0] + w2[1]) / denom;
}

// ---------------- finisher: one wave sums 256 pre-divided partials ----------------
__global__ __launch_bounds__(64) void smoothap_final(
    const float* __restrict__ partial, float* __restrict__ out)
{
    const int tid = threadIdx.x;
    float4 a = reinterpret_cast<const float4*>(partial)[tid];  // 64*4 = 256
    float v = (a.x + a.y) + (a.z + a.w);
    v += __shfl_xor(v, 1);
    v += __shfl_xor(v, 2);
    v += __shfl_xor(v, 4);
    v += __shfl_xor(v, 8);
    v += __shfl_xor(v, 16);
    v += __shfl_xor(v, 32);
    if (tid == 0) out[0] = 1.0f - v * (1.0f / 32.0f);
}

extern "C" void kernel_launch(void* const* d_in, const int* in_sizes, int n_in,
                              void* d_out, int out_size, void* d_ws, size_t ws_size,
                              hipStream_t stream) {
    const float* sim = (const float*)d_in[0];
    const float* tgt = (const float*)d_in[1];
    float* out = (float*)d_out;
    float* partial = (float*)d_ws;   // 256 floats (16B-aligned)

    smoothap_fused<<<dim3(NB), dim3(TPB), 0, stream>>>(sim, tgt, partial);
    smoothap_final<<<dim3(1), dim3(64), 0, stream>>>(partial, out);
}